// Round 10
// baseline (1422.118 us; speedup 1.0000x reference)
//
#include <hip/hip_runtime.h>

#define RNN_T 2048
#define RNN_B 64
#define RNN_H 256
#define KSTR 20   // floats per 16-row k-block (16 + 4 pad): 16B-aligned

typedef float v2f __attribute__((ext_vector_type(2)));

// ---------------------------------------------------------------------------
// Kernel 1: xproj[b,t,:] = embed[x[b,t]] @ Wx + b_fc   (written into hs region)
// ---------------------------------------------------------------------------
__global__ __launch_bounds__(256)
void xproj_kernel(const int* __restrict__ x, const float* __restrict__ embed,
                  const float* __restrict__ Wfc, const float* __restrict__ bfc,
                  float* __restrict__ hsb) {
    __shared__ int ixs[64];
    __shared__ __align__(16) float A[64][260];
    const int tid = threadIdx.x;
    const long rb0 = (long)blockIdx.x * 64;

    if (tid < 64) ixs[tid] = x[rb0 + tid];
    __syncthreads();

    {
        const int r = tid >> 2, q = tid & 3;
        const float* erow = embed + (long)ixs[r] * RNN_H;
        #pragma unroll
        for (int i = 0; i < 16; ++i) {
            const int c = q * 64 + i * 4;
            *(float4*)&A[r][c] = *(const float4*)(erow + c);
        }
    }
    __syncthreads();

    const int tj = tid & 31, tr = tid >> 5;
    const int r0 = tr * 8, j0 = tj * 4, j1 = 128 + tj * 4;

    float acc[8][8];
    #pragma unroll
    for (int i = 0; i < 8; ++i)
        #pragma unroll
        for (int c = 0; c < 8; ++c) acc[i][c] = 0.f;

    for (int k4 = 0; k4 < 64; ++k4) {
        float4 a[8];
        #pragma unroll
        for (int i = 0; i < 8; ++i) a[i] = *(const float4*)&A[r0 + i][k4 * 4];
        #pragma unroll
        for (int kk = 0; kk < 4; ++kk) {
            const int k = k4 * 4 + kk;
            const float4 wa = *(const float4*)(Wfc + (long)k * RNN_H + j0);
            const float4 wb = *(const float4*)(Wfc + (long)k * RNN_H + j1);
            #pragma unroll
            for (int i = 0; i < 8; ++i) {
                const float av = reinterpret_cast<const float*>(&a[i])[kk];
                acc[i][0] = fmaf(av, wa.x, acc[i][0]);
                acc[i][1] = fmaf(av, wa.y, acc[i][1]);
                acc[i][2] = fmaf(av, wa.z, acc[i][2]);
                acc[i][3] = fmaf(av, wa.w, acc[i][3]);
                acc[i][4] = fmaf(av, wb.x, acc[i][4]);
                acc[i][5] = fmaf(av, wb.y, acc[i][5]);
                acc[i][6] = fmaf(av, wb.z, acc[i][6]);
                acc[i][7] = fmaf(av, wb.w, acc[i][7]);
            }
        }
    }

    const float4 ba = *(const float4*)(bfc + j0);
    const float4 bb = *(const float4*)(bfc + j1);
    #pragma unroll
    for (int i = 0; i < 8; ++i) {
        const long row = rb0 + r0 + i;
        float4 o1 = make_float4(acc[i][0] + ba.x, acc[i][1] + ba.y,
                                acc[i][2] + ba.z, acc[i][3] + ba.w);
        float4 o2 = make_float4(acc[i][4] + bb.x, acc[i][5] + bb.y,
                                acc[i][6] + bb.z, acc[i][7] + bb.w);
        *(float4*)(hsb + row * RNN_H + j0) = o1;
        *(float4*)(hsb + row * RNN_H + j1) = o2;
    }
}

// DPP hops (VALU pipe). HW-verified in R9:
//   0xB1 = xor1, 0x4E = xor2, 0x128 ROW_ROR:8 = xor8,
//   xor4 = 0x1B then 0x141.
#define DPP_HOP(val, CTRL)                                                  \
    __int_as_float(__builtin_amdgcn_update_dpp(                             \
        0, __float_as_int(val), CTRL, 0xf, 0xf, true))

__device__ __forceinline__ v2f lo2(const float4 v) { return (v2f){v.x, v.y}; }
__device__ __forceinline__ v2f hi2(const float4 v) { return (v2f){v.z, v.w}; }

// LDS-only barrier: __syncthreads() drains vmcnt(0) too, putting the per-step
// global hs-store completion (~300cy) on the critical path. Our only cross-
// lane dependency is through LDS -> lgkmcnt(0) + s_barrier suffices. The
// "memory" clobber orders the surrounding ds_read/ds_write (they are memory
// ops, unlike rule #18's register-only MFMA case).
#define LDS_BARRIER() asm volatile("s_waitcnt lgkmcnt(0)\n\ts_barrier" ::: "memory")

// ---------------------------------------------------------------------------
// Kernel 2: persistent RNN scan. One WG per batch row, 1024 threads (16
// waves, 4/SIMD). Lane (w,l): s = l&15 -> rows k0 = s*16; col group
// cg = w*4 + (l>>4) -> 4 cols c0 = cg*4. 64 weight floats/lane as 32 v2f:
// fits the 128-VGPR budget, so v_pk_fma_f32 is legal (R9 lesson: AGPR-parked
// weights force VOP3P -> 2x scalar v_fma split: 890 VALU-cyc/step). In-loop
// asm "+v" pin forces continued VGPR residency (R5 lesson: a pre-loop pin
// lets the allocator park weights in AGPRs afterwards).
// Fused 16-way reduce + 4->1 col merge: stage1 xor1 mux bit0, stage2 xor2
// mux bit1, then pure-add xor8 (0x128) and xor4 (0x1B,0x141). Lane s ends
// with the full sum of col c0+(s&3); writers s<4.
// DS: 4 ds_read_b128/lane; h k-blocks stride 20 (2-way banks, free).
// Ping-pong h buffers; ONE LDS-only barrier/step.
// ---------------------------------------------------------------------------
__global__ __launch_bounds__(1024, 4)
void rnn_scan_kernel(const float* __restrict__ Wfc, const float* __restrict__ Wout,
                     const float* __restrict__ bout, float* __restrict__ out,
                     float* __restrict__ hsb) {
    __shared__ __align__(16) float hA[16 * KSTR];
    __shared__ __align__(16) float hB[16 * KSTR];
    const int tid = threadIdx.x;
    const int b = blockIdx.x;
    const int w = tid >> 6, l = tid & 63;
    const int s  = l & 15;               // k-sub group: rows s*16..s*16+15
    const int cg = w * 4 + (l >> 4);     // column group 0..63
    const int c0 = cg * 4;               // 4 columns
    const int k0 = s * 16;

    // weights: wv[c][m] = {Wh[k0+2m][c0+c], Wh[k0+2m+1][c0+c]}, c<4, m<8
    const float* Wh = Wfc + RNN_H * RNN_H;
    v2f wv[4][8];
    #pragma unroll
    for (int m = 0; m < 8; ++m) {
        const long kb = (long)(k0 + 2 * m) * RNN_H;
        #pragma unroll
        for (int c = 0; c < 4; ++c) {
            v2f t;
            t.x = Wh[kb + c0 + c];
            t.y = Wh[kb + RNN_H + c0 + c];
            wv[c][m] = t;
        }
    }

    if (tid < 16 * KSTR) hA[tid] = 0.f;

    float* xpb = hsb + (long)b * RNN_T * RNN_H;
    const bool wr = (s < 4);                             // 4 writers / 16-group
    const int jcol = c0 + (s & 3);                       // writer's column
    const int widx = (jcol >> 4) * KSTR + (jcol & 15);   // LDS write slot
    float* xw = xpb + jcol;                              // hs write cursor
    const float* xpf = xpb + jcol + 2 * RNN_H;           // prefetch cursor
    const float* xend = xpb + (long)RNN_T * RNN_H;

    float xr = 0.f, xn = 0.f;
    if (wr) { xr = xpb[jcol]; xn = xpb[RNN_H + jcol]; }
    __syncthreads();

    const float4* rdA = (const float4*)(hA + s * KSTR);
    const float4* rdB = (const float4*)(hB + s * KSTR);
    const bool m1 = (l & 1), m2 = (l & 2);

#define RNN_STEP(RD, WDST)                                                  \
    {                                                                       \
        float xf = 0.f;                                                     \
        if (wr && xpf < xend) xf = *xpf;                                    \
        xpf += RNN_H;                                                       \
        const float4 q0 = RD[0], q1 = RD[1], q2 = RD[2], q3 = RD[3];        \
        const v2f hp[8] = { lo2(q0), hi2(q0), lo2(q1), hi2(q1),             \
                            lo2(q2), hi2(q2), lo2(q3), hi2(q3) };           \
        v2f a0={0,0}, a1={0,0}, a2={0,0}, a3={0,0};                         \
        _Pragma("unroll")                                                   \
        for (int m = 0; m < 8; ++m) {                                       \
            a0 = __builtin_elementwise_fma(hp[m], wv[0][m], a0);            \
            a1 = __builtin_elementwise_fma(hp[m], wv[1][m], a1);            \
            a2 = __builtin_elementwise_fma(hp[m], wv[2][m], a2);            \
            a3 = __builtin_elementwise_fma(hp[m], wv[3][m], a3);            \
        }                                                                   \
        float s0 = a0.x + a0.y, s1 = a1.x + a1.y;                           \
        float s2 = a2.x + a2.y, s3 = a3.x + a3.y;                           \
        /* stage 1: xor1 (0xB1), 4 -> 2, mux bit0 */                        \
        float b0 = (m1 ? s1 : s0) + DPP_HOP(m1 ? s0 : s1, 0xB1);            \
        float b1 = (m1 ? s3 : s2) + DPP_HOP(m1 ? s2 : s3, 0xB1);            \
        /* stage 2: xor2 (0x4E), 2 -> 1, mux bit1 */                        \
        float cv = (m2 ? b1 : b0) + DPP_HOP(m2 ? b0 : b1, 0x4E);            \
        /* stage 3: xor8 pure add (ROW_ROR:8) */                            \
        cv += DPP_HOP(cv, 0x128);                                           \
        /* stage 4: xor4 pure add via 2-hop (0x1B then 0x141) */            \
        cv += DPP_HOP(DPP_HOP(cv, 0x1B), 0x141);                            \
        if (wr) {                                                           \
            const float vsum = cv + xr;                                     \
            const float e = __expf(2.f * vsum);                             \
            const float hn = 1.f - 2.f * __builtin_amdgcn_rcpf(e + 1.f);    \
            WDST[widx] = hn;                                                \
            *xw = hn;                                                       \
            xr = xn; xn = xf;                                               \
        }                                                                   \
        xw += RNN_H;                                                        \
        LDS_BARRIER();                                                      \
    }

    for (int t = 0; t < RNN_T; t += 2) {
        RNN_STEP(rdA, hB);     // even step: read hA, write hB
        RNN_STEP(rdB, hA);     // odd step:  read hB, write hA
        // re-pin weights in VGPRs every iteration: the uses above are
        // VOP3P (VGPR-only); this asm makes AGPR-parking unprofitable.
        #pragma unroll
        for (int m = 0; m < 8; ++m)
            asm volatile("" : "+v"(wv[0][m]), "+v"(wv[1][m]),
                              "+v"(wv[2][m]), "+v"(wv[3][m]));
    }
#undef RNN_STEP

    // epilogue: out[b,:] = h_last @ W_out + b_out  (h_last is in hA)
    if (tid < RNN_H) {
        float a0 = 0.f, a1 = 0.f, a2 = 0.f, a3 = 0.f;
        for (int k = 0; k < RNN_H; k += 4) {
            const int kb = (k >> 4) * KSTR + (k & 15);
            a0 = fmaf(hA[kb + 0], Wout[(long)(k + 0) * RNN_H + tid], a0);
            a1 = fmaf(hA[kb + 1], Wout[(long)(k + 1) * RNN_H + tid], a1);
            a2 = fmaf(hA[kb + 2], Wout[(long)(k + 2) * RNN_H + tid], a2);
            a3 = fmaf(hA[kb + 3], Wout[(long)(k + 3) * RNN_H + tid], a3);
        }
        out[(long)b * RNN_H + tid] = a0 + a1 + a2 + a3 + bout[tid];
    }
}

extern "C" void kernel_launch(void* const* d_in, const int* in_sizes, int n_in,
                              void* d_out, int out_size, void* d_ws, size_t ws_size,
                              hipStream_t stream) {
    const int*   x     = (const int*)d_in[0];
    const float* embed = (const float*)d_in[1];
    const float* Wfc   = (const float*)d_in[2];
    const float* bfc   = (const float*)d_in[3];
    const float* Wout  = (const float*)d_in[4];
    const float* bout  = (const float*)d_in[5];

    float* out = (float*)d_out;                 // [B, 256]
    float* hsb = out + RNN_B * RNN_H;           // [B, T, H] region

    xproj_kernel<<<(RNN_B * RNN_T) / 64, 256, 0, stream>>>(x, embed, Wfc, bfc, hsb);
    rnn_scan_kernel<<<RNN_B, 1024, 0, stream>>>(Wfc, Wout, bout, out, hsb);
}